// Round 1
// baseline (333.780 us; speedup 1.0000x reference)
//
#include <hip/hip_runtime.h>
#include <hip/hip_cooperative_groups.h>
#include <math.h>

namespace cg = cooperative_groups;

// SuperLoss: tau = mean(loss); y = max(-1/e, 5d), d = l - tau;
// w = W0(y); unclamped: out = d*e^{-w} + 0.1 w^2 = 0.1*w*(w+2)  [w e^w = y = 5d]
// clamped (5d < -1/e): w = -1, sigma = e -> out = e*d + 0.1  (exact closed form)
//
// W0 via single Pade[2/2] init in branch variable p = sqrt(2(e*y+1)):
//   (w+1)/p ~= (1 + 0.5p + 0.018055p^2)/(1 + 0.833323p + 0.143051p^2)
// max init err 0.0133 over p in [0,3.95]; one Newton step -> <= 7e-5.
//
// v2: single persistent cooperative kernel.
//   phase 1: grid-stride fp32 partial sums -> ws[block]
//   grid.sync()
//   phase 2: every block redundantly double-reduces the partials (8 KB, L2-hot)
//   phase 3: elementwise, same index mapping as phase 1 -> input re-reads hit L3
// Removes 3 inter-kernel launch gaps + the single-block finalize kernel.
// Fallback to the verified 4-kernel path if cooperative launch is unavailable.

#define TPB 256
#define MAXBLOCKS 2048
#define NPART 2048
#define E_F 2.7182818f
#define NEG_INV_E (-0.36787942f)

__device__ __forceinline__ float fast_rcp(float x) {
    return __builtin_amdgcn_rcpf(x);
}

__device__ __forceinline__ float superloss_elem(float l, float tau) {
    float d = l - tau;
    float t5 = 5.0f * d;
    float y = fmaxf(NEG_INV_E, t5);
    // p = sqrt(2*(e*y + 1)); clamp tiny negative from fp rounding at branch pt
    float ey1 = fmaf(E_F, y, 1.0f);
    float p2 = fmaxf(ey1 + ey1, 0.0f);
    float p = __builtin_amdgcn_sqrtf(p2);
    // Pade[2/2] for (w+1)/p
    float num = fmaf(p, fmaf(p, 0.018055f, 0.5f), 1.0f);
    float den = fmaf(p, fmaf(p, 0.143051f, 0.833323f), 1.0f);
    float wp1 = p * num * fast_rcp(den);     // w0 + 1 >= 0
    float w = wp1 - 1.0f;
    // One Newton step: w -= (w e^w - y) / (e^w (w+1))
    float ew = __expf(w);
    float f = fmaf(w, ew, -y);
    float den2 = fmaf(ew, wp1, 1e-4f);
    w = fmaf(-f, fast_rcp(den2), w);
    float out_u = 0.1f * (w * (w + 2.0f));   // w/5 + 0.1 w^2
    float out_c = fmaf(E_F, d, 0.1f);        // clamped: sigma = e, w = -1
    return (t5 < NEG_INV_E) ? out_c : out_u;
}

// ---------------- fused cooperative kernel ----------------

__global__ __launch_bounds__(TPB) void superloss_fused(
    const float4* __restrict__ x, float4* __restrict__ out,
    float* __restrict__ ws,
    const float* __restrict__ x_s, float* __restrict__ out_s,
    int n4, int n, int nblocks)
{
    const int tid = blockIdx.x * TPB + threadIdx.x;
    const int stride = nblocks * TPB;
    const int lane = threadIdx.x & 63;
    const int wv = threadIdx.x >> 6;

    // ---- phase 1: fp32 partial sums (same index mapping as phase 3) ----
    float s = 0.0f;
    for (int i = tid; i < n4; i += stride) {
        float4 v = x[i];
        s += (v.x + v.y) + (v.z + v.w);
    }
    if (blockIdx.x == 0 && threadIdx.x == 0) {
        for (int i = 4 * n4; i < n; ++i) s += x_s[i];
    }
#pragma unroll
    for (int off = 32; off > 0; off >>= 1) s += __shfl_down(s, off, 64);
    __shared__ float smem[4];
    if (lane == 0) smem[wv] = s;
    __syncthreads();
    if (threadIdx.x == 0) {
        ws[blockIdx.x] = (smem[0] + smem[1]) + (smem[2] + smem[3]);
    }

    cg::this_grid().sync();

    // ---- phase 2: every block redundantly reduces partials (double) ----
    double dacc = 0.0;
    for (int i = threadIdx.x; i < nblocks; i += TPB) dacc += (double)ws[i];
#pragma unroll
    for (int off = 32; off > 0; off >>= 1) dacc += __shfl_down(dacc, off, 64);
    __shared__ double dsm[4];
    if (lane == 0) dsm[wv] = dacc;
    __syncthreads();
    __shared__ float tau_sh;
    if (threadIdx.x == 0) {
        double total = (dsm[0] + dsm[1]) + (dsm[2] + dsm[3]);
        tau_sh = (float)(total / (double)n);
    }
    __syncthreads();
    const float tau = tau_sh;

    // ---- phase 3: elementwise (input re-read is L3-resident) ----
    for (int i = tid; i < n4; i += stride) {
        float4 v = x[i];
        float4 r;
        r.x = superloss_elem(v.x, tau);
        r.y = superloss_elem(v.y, tau);
        r.z = superloss_elem(v.z, tau);
        r.w = superloss_elem(v.w, tau);
        out[i] = r;
    }
    for (int i = 4 * n4 + tid; i < n; i += stride) {
        out_s[i] = superloss_elem(x_s[i], tau);
    }
}

// ---------------- fallback: verified 4-kernel path ----------------

__global__ void reduce_partial(const float4* __restrict__ x, float* __restrict__ partials,
                               int n4, const float* __restrict__ x_scalar, int n) {
    float s = 0.0f;
    int stride = gridDim.x * blockDim.x;
    for (int i = blockIdx.x * blockDim.x + threadIdx.x; i < n4; i += stride) {
        float4 v = x[i];
        s += (v.x + v.y) + (v.z + v.w);
    }
    if (blockIdx.x == 0 && threadIdx.x == 0) {
        for (int i = 4 * n4; i < n; ++i) s += x_scalar[i];
    }
#pragma unroll
    for (int off = 32; off > 0; off >>= 1) s += __shfl_down(s, off, 64);
    __shared__ float smem[4];
    int lane = threadIdx.x & 63;
    int wave = threadIdx.x >> 6;
    if (lane == 0) smem[wave] = s;
    __syncthreads();
    if (threadIdx.x == 0) {
        partials[blockIdx.x] = (smem[0] + smem[1]) + (smem[2] + smem[3]);
    }
}

__global__ void finalize_tau(const float* __restrict__ partials, float* __restrict__ tau_p, int n) {
    double s = 0.0;
    for (int i = threadIdx.x; i < NPART; i += 256) s += (double)partials[i];
#pragma unroll
    for (int off = 32; off > 0; off >>= 1) s += __shfl_down(s, off, 64);
    __shared__ double smem[4];
    int lane = threadIdx.x & 63;
    int wave = threadIdx.x >> 6;
    if (lane == 0) smem[wave] = s;
    __syncthreads();
    if (threadIdx.x == 0) {
        double total = (smem[0] + smem[1]) + (smem[2] + smem[3]);
        tau_p[0] = (float)(total / (double)n);
    }
}

__global__ void superloss_main(const float4* __restrict__ x, float4* __restrict__ out,
                               const float* __restrict__ tau_p, int n4) {
    int i = blockIdx.x * blockDim.x + threadIdx.x;
    if (i >= n4) return;
    float tau = *tau_p;
    float4 v = x[i];
    float4 r;
    r.x = superloss_elem(v.x, tau);
    r.y = superloss_elem(v.y, tau);
    r.z = superloss_elem(v.z, tau);
    r.w = superloss_elem(v.w, tau);
    out[i] = r;
}

__global__ void superloss_tail(const float* __restrict__ x, float* __restrict__ out,
                               const float* __restrict__ tau_p, int start, int n) {
    int i = start + blockIdx.x * blockDim.x + threadIdx.x;
    if (i < n) out[i] = superloss_elem(x[i], *tau_p);
}

extern "C" void kernel_launch(void* const* d_in, const int* in_sizes, int n_in,
                              void* d_out, int out_size, void* d_ws, size_t ws_size,
                              hipStream_t stream) {
    const float* loss = (const float*)d_in[0];
    float* out = (float*)d_out;
    int n = in_sizes[0];
    int n4 = n / 4;
    float* ws = (float*)d_ws;          // ws[0..blocks-1] partials (fallback: ws[NPART]=tau)

    // Co-residency sizing for the cooperative launch (host-side query; no sync).
    static int coop_blocks = -1;
    if (coop_blocks < 0) {
        int nb = 0;
        hipError_t e = hipOccupancyMaxActiveBlocksPerMultiprocessor(
            &nb, (const void*)superloss_fused, TPB, 0);
        if (e != hipSuccess || nb < 1) nb = 4;   // conservative floor
        long b = (long)nb * 256;                 // 256 CUs on MI355X
        if (b > MAXBLOCKS) b = MAXBLOCKS;
        if (b < 256) b = 256;
        coop_blocks = (int)b;
    }

    const float4* x4 = (const float4*)loss;
    float4* o4 = (float4*)out;
    const float* xs = loss;
    float* os = out;
    int nb_ = coop_blocks;
    void* args[] = {(void*)&x4, (void*)&o4, (void*)&ws, (void*)&xs, (void*)&os,
                    (void*)&n4, (void*)&n, (void*)&nb_};
    hipError_t err = hipLaunchCooperativeKernel((const void*)superloss_fused,
                                                dim3(coop_blocks), dim3(TPB),
                                                args, 0, stream);
    if (err != hipSuccess) {
        // Fallback: the previously verified 4-kernel path.
        float* tau_p = ws + NPART;
        reduce_partial<<<NPART, 256, 0, stream>>>((const float4*)loss, ws, n4, loss, n);
        finalize_tau<<<1, 256, 0, stream>>>(ws, tau_p, n);
        int blocks = (n4 + 255) / 256;
        superloss_main<<<blocks, 256, 0, stream>>>((const float4*)loss, (float4*)out, tau_p, n4);
        int tail = n - 4 * n4;
        if (tail > 0) {
            superloss_tail<<<(tail + 255) / 256, 256, 0, stream>>>(loss, out, tau_p, 4 * n4, n);
        }
    }
}

// Round 2
// 244.894 us; speedup vs baseline: 1.3630x; 1.3630x over previous
//
#include <hip/hip_runtime.h>
#include <math.h>

// SuperLoss: tau = mean(loss); y = max(-1/e, 5d), d = l - tau;
// w = W0(y); unclamped: out = d*e^{-w} + 0.1 w^2 = 0.1*w*(w+2)  [w e^w = y = 5d]
// clamped (5d < -1/e): w = -1, sigma = e -> out = e*d + 0.1  (exact closed form)
//
// W0 via single Pade[2/2] init in branch variable p = sqrt(2(e*y+1)):
//   (w+1)/p ~= (1 + 0.5p + 0.018055p^2)/(1 + 0.833323p + 0.143051p^2)
// max init err 0.0133 over p in [0,3.95]; one Newton step -> <= 7e-5.
//
// v3: two ordinary kernels, no cooperative barrier (v2's grid.sync() stalled
// the whole back half of the fused kernel: 213us @ 1.25 TB/s, VALUBusy 12%).
//   K1: 2048-block grid-stride fp32 partial sums -> ws[0..2047]  (proven fast)
//   K2: every block redundantly double-reduces the 2048 partials (8 KB, L2/L3
//       resident; bit-identical order to the old finalize_tau so tau is
//       unchanged), then elementwise float4 grid-stride. Removes the
//       single-block finalize launch + one inter-kernel gap, no atomics,
//       no workspace-zeroing assumptions (ws may be poisoned between runs).

#define NPART 2048
#define K2_BLOCKS 8192
#define E_F 2.7182818f
#define NEG_INV_E (-0.36787942f)

__device__ __forceinline__ float fast_rcp(float x) {
    return __builtin_amdgcn_rcpf(x);
}

__device__ __forceinline__ float superloss_elem(float l, float tau) {
    float d = l - tau;
    float t5 = 5.0f * d;
    float y = fmaxf(NEG_INV_E, t5);
    // p = sqrt(2*(e*y + 1)); clamp tiny negative from fp rounding at branch pt
    float ey1 = fmaf(E_F, y, 1.0f);
    float p2 = fmaxf(ey1 + ey1, 0.0f);
    float p = __builtin_amdgcn_sqrtf(p2);
    // Pade[2/2] for (w+1)/p
    float num = fmaf(p, fmaf(p, 0.018055f, 0.5f), 1.0f);
    float den = fmaf(p, fmaf(p, 0.143051f, 0.833323f), 1.0f);
    float wp1 = p * num * fast_rcp(den);     // w0 + 1 >= 0
    float w = wp1 - 1.0f;
    // One Newton step: w -= (w e^w - y) / (e^w (w+1))
    // Guard +1e-4: near branch f is rounding noise (~3e-8) while den2 -> 0;
    // 1e-4 caps the spurious step at ~3e-4 where dout/dw = 0.2*(w+1) ~ 0.
    float ew = __expf(w);
    float f = fmaf(w, ew, -y);
    float den2 = fmaf(ew, wp1, 1e-4f);
    w = fmaf(-f, fast_rcp(den2), w);
    float out_u = 0.1f * (w * (w + 2.0f));   // w/5 + 0.1 w^2
    float out_c = fmaf(E_F, d, 0.1f);        // clamped: sigma = e, w = -1
    return (t5 < NEG_INV_E) ? out_c : out_u;
}

// ---- K1: block partial sums (2048 partials in ws) ----
__global__ void reduce_partial(const float4* __restrict__ x, float* __restrict__ partials,
                               int n4, const float* __restrict__ x_scalar, int n) {
    float s = 0.0f;
    int stride = gridDim.x * blockDim.x;
    for (int i = blockIdx.x * blockDim.x + threadIdx.x; i < n4; i += stride) {
        float4 v = x[i];
        s += (v.x + v.y) + (v.z + v.w);
    }
    if (blockIdx.x == 0 && threadIdx.x == 0) {
        for (int i = 4 * n4; i < n; ++i) s += x_scalar[i];
    }
#pragma unroll
    for (int off = 32; off > 0; off >>= 1) s += __shfl_down(s, off, 64);
    __shared__ float smem[4];
    int lane = threadIdx.x & 63;
    int wave = threadIdx.x >> 6;
    if (lane == 0) smem[wave] = s;
    __syncthreads();
    if (threadIdx.x == 0) {
        partials[blockIdx.x] = (smem[0] + smem[1]) + (smem[2] + smem[3]);
    }
}

// ---- K2: redundant tau reduce (bit-identical to old finalize_tau) + elementwise ----
__global__ __launch_bounds__(256) void superloss_all(
    const float4* __restrict__ x, float4* __restrict__ out,
    const float* __restrict__ partials,
    const float* __restrict__ x_s, float* __restrict__ out_s,
    int n4, int n)
{
    // Prologue: every block computes tau from the 2048 partials.
    // Same accumulation order as the old finalize_tau kernel -> same bits,
    // and identical across blocks (deterministic).
    double s = 0.0;
    for (int i = threadIdx.x; i < NPART; i += 256) s += (double)partials[i];
#pragma unroll
    for (int off = 32; off > 0; off >>= 1) s += __shfl_down(s, off, 64);
    __shared__ double dsm[4];
    int lane = threadIdx.x & 63;
    int wave = threadIdx.x >> 6;
    if (lane == 0) dsm[wave] = s;
    __syncthreads();
    __shared__ float tau_sh;
    if (threadIdx.x == 0) {
        double total = (dsm[0] + dsm[1]) + (dsm[2] + dsm[3]);
        tau_sh = (float)(total / (double)n);
    }
    __syncthreads();
    const float tau = tau_sh;

    // Elementwise pass: input is L3-resident from K1's streaming read.
    const int stride = gridDim.x * blockDim.x;
    for (int i = blockIdx.x * blockDim.x + threadIdx.x; i < n4; i += stride) {
        float4 v = x[i];
        float4 r;
        r.x = superloss_elem(v.x, tau);
        r.y = superloss_elem(v.y, tau);
        r.z = superloss_elem(v.z, tau);
        r.w = superloss_elem(v.w, tau);
        out[i] = r;
    }
    for (int i = 4 * n4 + blockIdx.x * blockDim.x + threadIdx.x; i < n; i += stride) {
        out_s[i] = superloss_elem(x_s[i], tau);
    }
}

extern "C" void kernel_launch(void* const* d_in, const int* in_sizes, int n_in,
                              void* d_out, int out_size, void* d_ws, size_t ws_size,
                              hipStream_t stream) {
    const float* loss = (const float*)d_in[0];
    float* out = (float*)d_out;
    int n = in_sizes[0];
    int n4 = n / 4;
    float* ws = (float*)d_ws;          // ws[0..NPART-1] partials

    reduce_partial<<<NPART, 256, 0, stream>>>((const float4*)loss, ws, n4, loss, n);

    superloss_all<<<K2_BLOCKS, 256, 0, stream>>>(
        (const float4*)loss, (float4*)out, ws, loss, out, n4, n);
}